// Round 4
// baseline (650.836 us; speedup 1.0000x reference)
//
#include <hip/hip_runtime.h>
#include <hip/hip_bf16.h>
#include <hip/hip_cooperative_groups.h>
#include <math.h>

namespace cg = cooperative_groups;

#define B_  8
#define N_  1024
#define DM  512
#define H_  8
#define DK_ 64
#define ST  128

typedef __attribute__((ext_vector_type(8))) short short8;
typedef __attribute__((ext_vector_type(4))) float floatx4;

#define GLD16(gp, lp)                                                          \
    __builtin_amdgcn_global_load_lds(                                          \
        (const __attribute__((address_space(1))) void*)(gp),                   \
        (__attribute__((address_space(3))) void*)(lp), 16, 0, 0)

__device__ __forceinline__ float b2f(short u) {
    union { unsigned int i; float f; } c;
    c.i = ((unsigned int)(unsigned short)u) << 16;
    return c.f;
}
__device__ __forceinline__ unsigned short f2b(float f) {
    __hip_bfloat16 t = __float2bfloat16(f);
    return *(unsigned short*)&t;
}

// ===========================================================================
// Fused single cooperative kernel: cast -> qkv -> attn -> fc+LN.
// 256 blocks x 512 threads (1 block/CU, co-resident by construction).
// ===========================================================================
struct FusedArgs {
    const float* hidden;
    const float* rpe;
    const float* Wq;
    const float* Wk;
    const float* Wv;
    const float* fc_w;
    const float* fc_b;
    const float* ln_g;
    const float* ln_b;
    float* out;
    unsigned short* hb;
    unsigned short* wq;
    unsigned short* wk;
    unsigned short* wv;
    unsigned short* wf;
    unsigned short* qB;
    unsigned short* kB;
    unsigned short* vtB;
    unsigned short* cb;
};

#define SMEM_BYTES 71680

__global__ __launch_bounds__(512, 2)
void fused_all(FusedArgs a)
{
    __shared__ __align__(16) unsigned char smem[SMEM_BYTES];
    cg::grid_group grid = cg::this_grid();

    const int tid  = threadIdx.x;
    const int bid  = blockIdx.x;
    const int lane = tid & 63;
    const int wave = tid >> 6;
    const int lx   = lane & 15;
    const int quad = lane >> 4;
    const int mrow = lx;
    const int koff = quad * 8;

    // ---------------- Phase 0: cast fp32 -> bf16 -------------------------
    {
        const float* wsrc[4] = { a.Wq, a.Wk, a.Wv, a.fc_w };
        unsigned short* wdst[4] = { a.wq, a.wk, a.wv, a.wf };
        const int gid = bid * 512 + tid;
        #pragma unroll
        for (int it = 0; it < 5; ++it) {
            const int idx = it * 131072 + gid;
            const float* s;
            unsigned short* d;
            int off;
            if (idx < 524288) { s = a.hidden; d = a.hb; off = idx; }
            else {
                const int r2 = idx - 524288;
                const int sl = r2 >> 15;
                s = wsrc[sl]; d = wdst[sl]; off = r2 & 32767;
            }
            const int i = off * 8;
            float4 x0 = *(const float4*)&s[i];
            float4 x1 = *(const float4*)&s[i + 4];
            ushort4 o0, o1;
            o0.x = f2b(x0.x); o0.y = f2b(x0.y); o0.z = f2b(x0.z); o0.w = f2b(x0.w);
            o1.x = f2b(x1.x); o1.y = f2b(x1.y); o1.z = f2b(x1.z); o1.w = f2b(x1.w);
            *(ushort4*)&d[i] = o0;
            *(ushort4*)&d[i + 4] = o1;
        }
    }
    __threadfence();
    grid.sync();

    // ---------------- Phase 1: QKV GEMM (3 x 128x128 tile jobs) ----------
    {
        unsigned short* As = (unsigned short*)smem;          // 2*128*32
        unsigned short* Bs = As + 8192;                      // 2*128*32
        unsigned short* A0 = As;  unsigned short* A1 = As + 4096;
        unsigned short* B0 = Bs;  unsigned short* B1 = Bs + 4096;
        const int wm = wave >> 2;        // 0..1 -> 64-row half
        const int wn = wave & 3;         // 0..3 -> 32-col quarter
        const int srow = tid >> 2;       // 0..127
        const int skq  = (tid & 3) * 8;
        const int rq   = quad * 4;

        for (int t = 0; t < 3; ++t) {
            const int jid = t * 256 + bid;          // 0..767
            const int by  = jid >> 6;               // 0..11
            const int sel = by >> 2;
            const int n0  = (by & 3) * 128;
            const int m0  = (jid & 63) * 128;
            const unsigned short* W =
                (sel == 0) ? a.wq : (sel == 1 ? a.wk : a.wv);
            const unsigned short* Ag = a.hb + (size_t)(m0 + srow) * 512 + skq;
            const unsigned short* Bg = W + (size_t)(n0 + srow) * 512 + skq;

            floatx4 acc[4][2];
            #pragma unroll
            for (int i = 0; i < 4; ++i)
                #pragma unroll
                for (int j = 0; j < 2; ++j)
                    acc[i][j] = (floatx4){0.f, 0.f, 0.f, 0.f};

#define QSTAGE(Ad, Bd, off)                                                    \
    do {                                                                       \
        GLD16(Ag + (off), &(Ad)[tid * 8]);                                     \
        GLD16(Bg + (off), &(Bd)[tid * 8]);                                     \
    } while (0)
#define QSTEP(Ad, Bd)                                                          \
    do {                                                                       \
        short8 af[4], bf[2];                                                   \
        _Pragma("unroll")                                                      \
        for (int tt = 0; tt < 4; ++tt)                                         \
            af[tt] = *(const short8*)&(Ad)[(wm * 64 + tt * 16 + mrow) * 32 + koff];\
        _Pragma("unroll")                                                      \
        for (int tt = 0; tt < 2; ++tt)                                         \
            bf[tt] = *(const short8*)&(Bd)[(wn * 32 + tt * 16 + mrow) * 32 + koff];\
        _Pragma("unroll")                                                      \
        for (int mt = 0; mt < 4; ++mt)                                         \
            _Pragma("unroll")                                                  \
            for (int nt = 0; nt < 2; ++nt)                                     \
                acc[mt][nt] = __builtin_amdgcn_mfma_f32_16x16x32_bf16(         \
                    af[mt], bf[nt], acc[mt][nt], 0, 0, 0);                     \
    } while (0)

            QSTAGE(A0, B0, 0);
            __syncthreads();
            #pragma unroll
            for (int kt = 0; kt < 512; kt += 64) {
                QSTAGE(A1, B1, kt + 32);
                QSTEP(A0, B0);
                __syncthreads();
                if (kt + 64 < 512)
                    QSTAGE(A0, B0, kt + 64);
                QSTEP(A1, B1);
                __syncthreads();
            }
#undef QSTAGE
#undef QSTEP

            if (sel == 2) {
                #pragma unroll
                for (int mt = 0; mt < 4; ++mt) {
                    const int mr = m0 + wm * 64 + mt * 16 + rq;
                    const int bb = mr >> 10, tok = mr & 1023;
                    #pragma unroll
                    for (int nt = 0; nt < 2; ++nt) {
                        const int c = n0 + wn * 32 + nt * 16 + lx;
                        const int hh = c >> 6, d = c & 63;
                        ushort4 pk;
                        pk.x = f2b(acc[mt][nt][0]); pk.y = f2b(acc[mt][nt][1]);
                        pk.z = f2b(acc[mt][nt][2]); pk.w = f2b(acc[mt][nt][3]);
                        *(ushort4*)&a.vtB[((size_t)(bb * H_ + hh) * DK_ + d) * N_ + tok] = pk;
                    }
                }
            } else {
                unsigned short* O = (sel == 0) ? a.qB : a.kB;
                #pragma unroll
                for (int mt = 0; mt < 4; ++mt) {
                    const int mr = m0 + wm * 64 + mt * 16 + rq;
                    const int bb = mr >> 10, tok = mr & 1023;
                    #pragma unroll
                    for (int nt = 0; nt < 2; ++nt) {
                        const int c = n0 + wn * 32 + nt * 16 + lx;
                        const int hh = c >> 6, d = c & 63;
                        unsigned short* p =
                            O + ((size_t)(bb * H_ + hh) * N_ + tok) * DK_ + d;
                        #pragma unroll
                        for (int r = 0; r < 4; ++r)
                            p[(size_t)r * DK_] = f2b(acc[mt][nt][r]);
                    }
                }
            }
            __syncthreads();
        }
    }
    __threadfence();
    grid.sync();

    // ---------------- Phase 2: attention (2 x 128-query jobs) ------------
    {
        unsigned short* P  = (unsigned short*)smem;     // 128*136 shorts
        unsigned short* Vd = P + 128 * 136;             // 64*136 shorts
        const int w = wave;                             // 0..7: rows w*16..+15

        for (int jj = 0; jj < 2; ++jj) {
            const int jid = jj * 256 + bid;             // 0..511
            const int qb  = (jid & 7) * 128;
            const int bh  = jid >> 3;                   // 0..63
            const int h   = bh & 7, b = bh >> 3;
            const unsigned short* qh  = a.qB  + (size_t)bh * N_ * DK_;
            const unsigned short* kh  = a.kB  + (size_t)bh * N_ * DK_;
            const unsigned short* vth = a.vtB + (size_t)bh * DK_ * N_;
            const float* rp = a.rpe + ((size_t)bh * N_ + qb) * N_;
            const bool has_self = (qb >= ST);

            __syncthreads();   // protect LDS reuse across jobs

            if (has_self) {
                const int d = tid >> 3, t16 = (tid & 7) * 16;
                const unsigned short* vs = vth + (size_t)d * N_ + qb + t16;
                *(short8*)&Vd[d * 136 + t16]     = *(const short8*)vs;
                *(short8*)&Vd[d * 136 + t16 + 8] = *(const short8*)(vs + 8);
            }

            float sself = -1e30f;
            if (has_self) {
                const int i = qb + w * 16 + lx;
                const unsigned short* qr = qh + (size_t)i * DK_ + quad * 16;
                const unsigned short* kr = kh + (size_t)i * DK_ + quad * 16;
                short8 q0 = *(const short8*)qr, q1 = *(const short8*)(qr + 8);
                short8 k0 = *(const short8*)kr, k1 = *(const short8*)(kr + 8);
                float dot = 0.f;
                #pragma unroll
                for (int j = 0; j < 8; ++j) {
                    dot = fmaf(b2f(q0[j]), b2f(k0[j]), dot);
                    dot = fmaf(b2f(q1[j]), b2f(k1[j]), dot);
                }
                dot += __shfl_xor(dot, 16, 64);
                dot += __shfl_xor(dot, 32, 64);
                const float rd = rp[(size_t)(w * 16 + lx) * N_ + i];
                sself = (dot + rd) * 0.125f;
            }

            float rv[4][8];
            {
                const float* rbase = rp + (size_t)(w * 16 + quad * 4) * N_ + lx;
                #pragma unroll
                for (int r = 0; r < 4; ++r)
                    #pragma unroll
                    for (int nt = 0; nt < 8; ++nt)
                        rv[r][nt] = rbase[(size_t)r * N_ + nt * 16];
            }

            short8 aq[2];
            {
                const unsigned short* qrow =
                    qh + (size_t)(qb + w * 16 + lx) * DK_ + quad * 8;
                aq[0] = *(const short8*)qrow;
                aq[1] = *(const short8*)(qrow + 32);
            }
            floatx4 sacc[8];
            #pragma unroll
            for (int nt = 0; nt < 8; ++nt) sacc[nt] = (floatx4){0.f, 0.f, 0.f, 0.f};
            #pragma unroll
            for (int nt = 0; nt < 8; ++nt) {
                const unsigned short* krow =
                    kh + (size_t)(nt * 16 + lx) * DK_ + quad * 8;
                short8 b0 = *(const short8*)krow;
                short8 b1 = *(const short8*)(krow + 32);
                sacc[nt] = __builtin_amdgcn_mfma_f32_16x16x32_bf16(aq[0], b0, sacc[nt], 0, 0, 0);
                sacc[nt] = __builtin_amdgcn_mfma_f32_16x16x32_bf16(aq[1], b1, sacc[nt], 0, 0, 0);
            }

            float l4[4], ps4[4];
            #pragma unroll
            for (int r = 0; r < 4; ++r) {
                float sv[8];
                float mx = -1e30f;
                #pragma unroll
                for (int nt = 0; nt < 8; ++nt) {
                    sv[nt] = (sacc[nt][r] + rv[r][nt]) * 0.125f;
                    mx = fmaxf(mx, sv[nt]);
                }
                #pragma unroll
                for (int o = 1; o < 16; o <<= 1)
                    mx = fmaxf(mx, __shfl_xor(mx, o, 64));
                const float ss = __shfl(sself, quad * 4 + r, 64);
                mx = fmaxf(mx, ss);
                float sum = 0.f;
                #pragma unroll
                for (int nt = 0; nt < 8; ++nt) {
                    sv[nt] = __expf(sv[nt] - mx);
                    sum += sv[nt];
                }
                #pragma unroll
                for (int o = 1; o < 16; o <<= 1)
                    sum += __shfl_xor(sum, o, 64);
                const float ps = has_self ? __expf(ss - mx) : 0.f;
                l4[r] = sum + ps;
                ps4[r] = ps;
                const int row = w * 16 + quad * 4 + r;
                #pragma unroll
                for (int nt = 0; nt < 8; ++nt)
                    P[row * 136 + nt * 16 + lx] = f2b(sv[nt]);
            }
            __syncthreads();

            short8 ap[4];
            #pragma unroll
            for (int ks = 0; ks < 4; ++ks)
                ap[ks] = *(const short8*)&P[(w * 16 + lx) * 136 + ks * 32 + quad * 8];
            floatx4 oacc[4];
            #pragma unroll
            for (int nt = 0; nt < 4; ++nt) oacc[nt] = (floatx4){0.f, 0.f, 0.f, 0.f};
            #pragma unroll
            for (int nt = 0; nt < 4; ++nt) {
                const unsigned short* vrow = vth + (size_t)(nt * 16 + lx) * N_;
                #pragma unroll
                for (int ks = 0; ks < 4; ++ks) {
                    short8 bv = *(const short8*)(vrow + ks * 32 + quad * 8);
                    oacc[nt] = __builtin_amdgcn_mfma_f32_16x16x32_bf16(ap[ks], bv, oacc[nt], 0, 0, 0);
                }
            }

            #pragma unroll
            for (int r = 0; r < 4; ++r) {
                const int il = w * 16 + quad * 4 + r;
                const int i = qb + il;
                const float inv = 1.0f / l4[r];
                const float ps = ps4[r];
                #pragma unroll
                for (int nt = 0; nt < 4; ++nt) {
                    const int d = nt * 16 + lx;
                    float o = oacc[nt][r];
                    if (has_self)
                        o = fmaf(ps, b2f((short)Vd[d * 136 + il]), o);
                    a.cb[((size_t)(b * N_) + i) * DM + h * DK_ + d] = f2b(o * inv);
                }
            }
            __syncthreads();
        }
    }
    __threadfence();
    grid.sync();

    // ---------------- Phase 3: FC + residual + LayerNorm -----------------
    {
        unsigned short* As = (unsigned short*)smem;          // 2*32*32 shorts
        unsigned short* Bs = As + 2048;                      // 2*512*32 shorts
        float* lsum = (float*)(smem + 69632);                // [32][8]
        float* lsq  = (float*)(smem + 70656);                // [32][8]
        unsigned short* A0 = As;  unsigned short* A1 = As + 1024;
        unsigned short* B0 = Bs;  unsigned short* B1 = Bs + 16384;

        const int wv   = wave;               // 0..7 -> col block wv*64
        const int m0   = bid * 32;
        const int srow = tid >> 2;
        const int skq  = (tid & 3) * 8;
        const unsigned short* Ag = a.cb + (size_t)(m0 + srow) * 512 + skq;
        const unsigned short* Bg = a.wf + (size_t)srow * 512 + skq;

#define FSTAGE(Ad, Bd, off)                                                    \
    do {                                                                       \
        if (tid < 128) GLD16(Ag + (off), &(Ad)[tid * 8]);                      \
        _Pragma("unroll")                                                      \
        for (int p = 0; p < 4; ++p)                                            \
            GLD16(Bg + (size_t)p * 128 * 512 + (off),                          \
                  &(Bd)[p * 4096 + tid * 8]);                                  \
    } while (0)
#define FSTEP(Ad, Bd)                                                          \
    do {                                                                       \
        short8 af[2], bf[4];                                                   \
        _Pragma("unroll")                                                      \
        for (int tt = 0; tt < 2; ++tt)                                         \
            af[tt] = *(const short8*)&(Ad)[(tt * 16 + mrow) * 32 + koff];      \
        _Pragma("unroll")                                                      \
        for (int tt = 0; tt < 4; ++tt)                                         \
            bf[tt] = *(const short8*)&(Bd)[(wv * 64 + tt * 16 + mrow) * 32 + koff];\
        _Pragma("unroll")                                                      \
        for (int mt = 0; mt < 2; ++mt)                                         \
            _Pragma("unroll")                                                  \
            for (int nt = 0; nt < 4; ++nt)                                     \
                acc[mt][nt] = __builtin_amdgcn_mfma_f32_16x16x32_bf16(         \
                    af[mt], bf[nt], acc[mt][nt], 0, 0, 0);                     \
    } while (0)

        floatx4 acc[2][4];
        #pragma unroll
        for (int i = 0; i < 2; ++i)
            #pragma unroll
            for (int j = 0; j < 4; ++j)
                acc[i][j] = (floatx4){0.f, 0.f, 0.f, 0.f};

        FSTAGE(A0, B0, 0);
        __syncthreads();
        #pragma unroll
        for (int kt = 0; kt < 512; kt += 64) {
            FSTAGE(A1, B1, kt + 32);
            FSTEP(A0, B0);
            __syncthreads();
            if (kt + 64 < 512)
                FSTAGE(A0, B0, kt + 64);
            FSTEP(A1, B1);
            __syncthreads();
        }
#undef FSTAGE
#undef FSTEP

        float s[2][4], ss[2][4];
        #pragma unroll
        for (int mt = 0; mt < 2; ++mt)
            #pragma unroll
            for (int r = 0; r < 4; ++r) { s[mt][r] = 0.f; ss[mt][r] = 0.f; }

        #pragma unroll
        for (int mt = 0; mt < 2; ++mt)
            #pragma unroll
            for (int nt = 0; nt < 4; ++nt) {
                const int c = wv * 64 + nt * 16 + lx;
                const float bvv = a.fc_b[c];
                #pragma unroll
                for (int r = 0; r < 4; ++r) {
                    const size_t row = (size_t)(m0 + mt * 16 + quad * 4 + r);
                    float v = acc[mt][nt][r] + bvv + a.hidden[row * 512 + c];
                    acc[mt][nt][r] = v;
                    s[mt][r] += v;
                    ss[mt][r] = fmaf(v, v, ss[mt][r]);
                }
            }

        #pragma unroll
        for (int o = 1; o < 16; o <<= 1)
            #pragma unroll
            for (int mt = 0; mt < 2; ++mt)
                #pragma unroll
                for (int r = 0; r < 4; ++r) {
                    s[mt][r]  += __shfl_xor(s[mt][r],  o, 64);
                    ss[mt][r] += __shfl_xor(ss[mt][r], o, 64);
                }
        if (lx == 0) {
            #pragma unroll
            for (int mt = 0; mt < 2; ++mt)
                #pragma unroll
                for (int r = 0; r < 4; ++r) {
                    lsum[(mt * 16 + quad * 4 + r) * 8 + wv] = s[mt][r];
                    lsq [(mt * 16 + quad * 4 + r) * 8 + wv] = ss[mt][r];
                }
        }
        __syncthreads();

        #pragma unroll
        for (int mt = 0; mt < 2; ++mt)
            #pragma unroll
            for (int r = 0; r < 4; ++r) {
                const int rl = mt * 16 + quad * 4 + r;
                float ts = 0.f, tss = 0.f;
                #pragma unroll
                for (int u = 0; u < 8; ++u) {
                    ts += lsum[rl * 8 + u]; tss += lsq[rl * 8 + u];
                }
                const float mean = ts * (1.0f / DM);
                const float var  = tss * (1.0f / DM) - mean * mean;
                const float rstd = rsqrtf(var + 1e-6f);
                const size_t row = (size_t)(m0 + rl);
                #pragma unroll
                for (int nt = 0; nt < 4; ++nt) {
                    const int c = wv * 64 + nt * 16 + lx;
                    a.out[row * 512 + c] =
                        (acc[mt][nt][r] - mean) * rstd * a.ln_g[c] + a.ln_b[c];
                }
            }
    }
}

// ===========================================================================
// Fallback path: round-2 four-kernel pipeline (proven 390 us) in case the
// cooperative launch is rejected under graph capture.
// ===========================================================================
struct CastArgs {
    const float* src[5];
    unsigned short* dst[5];
};

__global__ __launch_bounds__(256)
void cast_bf16_kernel(CastArgs a)
{
    const int bx = blockIdx.x;
    int j, base;
    if (bx < 2048) { j = 0; base = bx; }
    else { const int r = bx - 2048; j = 1 + (r >> 7); base = r & 127; }
    const float* __restrict__ s = a.src[j];
    unsigned short* __restrict__ d = a.dst[j];
    const int i = (base * 256 + threadIdx.x) * 8;
    float4 x0 = *(const float4*)&s[i];
    float4 x1 = *(const float4*)&s[i + 4];
    ushort4 o0, o1;
    o0.x = f2b(x0.x); o0.y = f2b(x0.y); o0.z = f2b(x0.z); o0.w = f2b(x0.w);
    o1.x = f2b(x1.x); o1.y = f2b(x1.y); o1.z = f2b(x1.z); o1.w = f2b(x1.w);
    *(ushort4*)&d[i] = o0;
    *(ushort4*)&d[i + 4] = o1;
}

__device__ __forceinline__
void gemm_step(const unsigned short* Ac, const unsigned short* Bc,
               int wm, int wn, int mrow, int koff, floatx4 acc[4][4])
{
    short8 af[4], bf[4];
    #pragma unroll
    for (int t = 0; t < 4; ++t) {
        af[t] = *(const short8*)&Ac[(wm * 64 + t * 16 + mrow) * 32 + koff];
        bf[t] = *(const short8*)&Bc[(wn * 64 + t * 16 + mrow) * 32 + koff];
    }
    #pragma unroll
    for (int mt = 0; mt < 4; ++mt)
        #pragma unroll
        for (int nt = 0; nt < 4; ++nt)
            acc[mt][nt] = __builtin_amdgcn_mfma_f32_16x16x32_bf16(
                af[mt], bf[nt], acc[mt][nt], 0, 0, 0);
}

__device__ __forceinline__
void gemm_core(const unsigned short* __restrict__ A,
               const unsigned short* __restrict__ W,
               int m0, int n0, unsigned short* As, unsigned short* Bs,
               floatx4 acc[4][4])
{
    const int tid = threadIdx.x;
    const int lane = tid & 63;
    const int wave = tid >> 6;
    const int wm = wave >> 1, wn = wave & 1;
    const int srow = tid >> 2;
    const int skq  = (tid & 3) * 8;
    const unsigned short* Ag = A + (size_t)(m0 + srow) * 512 + skq;
    const unsigned short* Bg = W + (size_t)(n0 + srow) * 512 + skq;
    const int mrow = lane & 15;
    const int koff = (lane >> 4) * 8;

    unsigned short* A0 = As;        unsigned short* A1 = As + 4096;
    unsigned short* B0 = Bs;        unsigned short* B1 = Bs + 4096;

#define STAGE4(Ad, Bd, off)                                                    \
    do {                                                                       \
        GLD16(Ag + (off),            &(Ad)[tid * 8]);                          \
        GLD16(Ag + 64 * 512 + (off), &(Ad)[2048 + tid * 8]);                   \
        GLD16(Bg + (off),            &(Bd)[tid * 8]);                          \
        GLD16(Bg + 64 * 512 + (off), &(Bd)[2048 + tid * 8]);                   \
    } while (0)

    STAGE4(A0, B0, 0);
    __syncthreads();

    #pragma unroll
    for (int kt = 0; kt < 512; kt += 64) {
        STAGE4(A1, B1, kt + 32);
        gemm_step(A0, B0, wm, wn, mrow, koff, acc);
        __syncthreads();
        if (kt + 64 < 512)
            STAGE4(A0, B0, kt + 64);
        gemm_step(A1, B1, wm, wn, mrow, koff, acc);
        __syncthreads();
    }
#undef STAGE4
}

__global__ __launch_bounds__(256)
void qkv_gemm_kernel(const unsigned short* __restrict__ A,
                     const unsigned short* __restrict__ W0,
                     const unsigned short* __restrict__ W1,
                     const unsigned short* __restrict__ W2,
                     unsigned short* __restrict__ qo,
                     unsigned short* __restrict__ ko,
                     unsigned short* __restrict__ vto)
{
    __shared__ __align__(16) unsigned short As[2 * 128 * 32];
    __shared__ __align__(16) unsigned short Bs[2 * 128 * 32];
    const int by = blockIdx.y;
    const int sel = by >> 2;
    const unsigned short* W = (sel == 0) ? W0 : (sel == 1 ? W1 : W2);
    const int m0 = blockIdx.x * 128;
    const int n0 = (by & 3) * 128;

    floatx4 acc[4][4];
    #pragma unroll
    for (int i = 0; i < 4; ++i)
        #pragma unroll
        for (int j = 0; j < 4; ++j)
            acc[i][j] = (floatx4){0.f, 0.f, 0.f, 0.f};

    gemm_core(A, W, m0, n0, As, Bs, acc);

    const int lane = threadIdx.x & 63;
    const int wave = threadIdx.x >> 6;
    const int wm = wave >> 1, wn = wave & 1;
    const int lx = lane & 15;
    const int rq = (lane >> 4) * 4;

    if (sel == 2) {
        #pragma unroll
        for (int mt = 0; mt < 4; ++mt) {
            const int mrow = m0 + wm * 64 + mt * 16 + rq;
            const int bb = mrow >> 10, tok = mrow & 1023;
            #pragma unroll
            for (int nt = 0; nt < 4; ++nt) {
                const int c = n0 + wn * 64 + nt * 16 + lx;
                const int hh = c >> 6, d = c & 63;
                ushort4 pk;
                pk.x = f2b(acc[mt][nt][0]); pk.y = f2b(acc[mt][nt][1]);
                pk.z = f2b(acc[mt][nt][2]); pk.w = f2b(acc[mt][nt][3]);
                *(ushort4*)&vto[((size_t)(bb * H_ + hh) * DK_ + d) * N_ + tok] = pk;
            }
        }
    } else {
        unsigned short* O = (sel == 0) ? qo : ko;
        #pragma unroll
        for (int mt = 0; mt < 4; ++mt) {
            const int mrow = m0 + wm * 64 + mt * 16 + rq;
            const int bb = mrow >> 10, tok = mrow & 1023;
            #pragma unroll
            for (int nt = 0; nt < 4; ++nt) {
                const int c = n0 + wn * 64 + nt * 16 + lx;
                const int hh = c >> 6, d = c & 63;
                unsigned short* p =
                    O + ((size_t)(bb * H_ + hh) * N_ + tok) * DK_ + d;
                #pragma unroll
                for (int r = 0; r < 4; ++r)
                    p[(size_t)r * DK_] = f2b(acc[mt][nt][r]);
            }
        }
    }
}

__global__ __launch_bounds__(256)
void attn_kernel(const unsigned short* __restrict__ qg,
                 const unsigned short* __restrict__ kg,
                 const unsigned short* __restrict__ vtg,
                 const float* __restrict__ rpe,
                 unsigned short* __restrict__ ctx)
{
    __shared__ __align__(16) unsigned short P[64 * 136];
    __shared__ __align__(16) unsigned short Vd[64 * 72];

    const int tid  = threadIdx.x;
    const int lane = tid & 63;
    const int w    = tid >> 6;
    const int lx   = lane & 15;
    const int quad = lane >> 4;
    const int qb = blockIdx.x * 64;
    const int h  = blockIdx.y, b = blockIdx.z;
    const int bh = b * H_ + h;
    const unsigned short* qh  = qg  + (size_t)bh * N_ * DK_;
    const unsigned short* kh  = kg  + (size_t)bh * N_ * DK_;
    const unsigned short* vth = vtg + (size_t)bh * DK_ * N_;
    const float* rp = rpe + ((size_t)bh * N_ + qb) * N_;
    const bool has_self = (qb >= ST);

    if (has_self) {
        const int d = tid >> 2, t16 = (tid & 3) * 16;
        const unsigned short* vs = vth + (size_t)d * N_ + qb + t16;
        *(short8*)&Vd[d * 72 + t16]     = *(const short8*)vs;
        *(short8*)&Vd[d * 72 + t16 + 8] = *(const short8*)(vs + 8);
    }

    float sself = -1e30f;
    if (has_self) {
        const int i = qb + w * 16 + lx;
        const unsigned short* qr = qh + (size_t)i * DK_ + quad * 16;
        const unsigned short* kr = kh + (size_t)i * DK_ + quad * 16;
        short8 q0 = *(const short8*)qr, q1 = *(const short8*)(qr + 8);
        short8 k0 = *(const short8*)kr, k1 = *(const short8*)(kr + 8);
        float dot = 0.f;
        #pragma unroll
        for (int j = 0; j < 8; ++j) {
            dot = fmaf(b2f(q0[j]), b2f(k0[j]), dot);
            dot = fmaf(b2f(q1[j]), b2f(k1[j]), dot);
        }
        dot += __shfl_xor(dot, 16, 64);
        dot += __shfl_xor(dot, 32, 64);
        const float rd = rp[(size_t)(w * 16 + lx) * N_ + i];
        sself = (dot + rd) * 0.125f;
    }

    float rv[4][8];
    {
        const float* rbase = rp + (size_t)(w * 16 + quad * 4) * N_ + lx;
        #pragma unroll
        for (int r = 0; r < 4; ++r)
            #pragma unroll
            for (int nt = 0; nt < 8; ++nt)
                rv[r][nt] = rbase[(size_t)r * N_ + nt * 16];
    }

    short8 aq[2];
    {
        const unsigned short* qrow =
            qh + (size_t)(qb + w * 16 + lx) * DK_ + quad * 8;
        aq[0] = *(const short8*)qrow;
        aq[1] = *(const short8*)(qrow + 32);
    }
    floatx4 sacc[8];
    #pragma unroll
    for (int nt = 0; nt < 8; ++nt) sacc[nt] = (floatx4){0.f, 0.f, 0.f, 0.f};
    #pragma unroll
    for (int nt = 0; nt < 8; ++nt) {
        const unsigned short* krow =
            kh + (size_t)(nt * 16 + lx) * DK_ + quad * 8;
        short8 b0 = *(const short8*)krow;
        short8 b1 = *(const short8*)(krow + 32);
        sacc[nt] = __builtin_amdgcn_mfma_f32_16x16x32_bf16(aq[0], b0, sacc[nt], 0, 0, 0);
        sacc[nt] = __builtin_amdgcn_mfma_f32_16x16x32_bf16(aq[1], b1, sacc[nt], 0, 0, 0);
    }

    float l4[4], ps4[4];
    #pragma unroll
    for (int r = 0; r < 4; ++r) {
        float sv[8];
        float mx = -1e30f;
        #pragma unroll
        for (int nt = 0; nt < 8; ++nt) {
            sv[nt] = (sacc[nt][r] + rv[r][nt]) * 0.125f;
            mx = fmaxf(mx, sv[nt]);
        }
        #pragma unroll
        for (int o = 1; o < 16; o <<= 1)
            mx = fmaxf(mx, __shfl_xor(mx, o, 64));
        const float ss = __shfl(sself, quad * 4 + r, 64);
        mx = fmaxf(mx, ss);
        float sum = 0.f;
        #pragma unroll
        for (int nt = 0; nt < 8; ++nt) {
            sv[nt] = __expf(sv[nt] - mx);
            sum += sv[nt];
        }
        #pragma unroll
        for (int o = 1; o < 16; o <<= 1)
            sum += __shfl_xor(sum, o, 64);
        const float ps = has_self ? __expf(ss - mx) : 0.f;
        l4[r] = sum + ps;
        ps4[r] = ps;
        const int row = w * 16 + quad * 4 + r;
        #pragma unroll
        for (int nt = 0; nt < 8; ++nt)
            P[row * 136 + nt * 16 + lx] = f2b(sv[nt]);
    }
    __syncthreads();

    short8 ap[4];
    #pragma unroll
    for (int ks = 0; ks < 4; ++ks)
        ap[ks] = *(const short8*)&P[(w * 16 + lx) * 136 + ks * 32 + quad * 8];
    floatx4 oacc[4];
    #pragma unroll
    for (int nt = 0; nt < 4; ++nt) oacc[nt] = (floatx4){0.f, 0.f, 0.f, 0.f};
    #pragma unroll
    for (int nt = 0; nt < 4; ++nt) {
        const unsigned short* vrow = vth + (size_t)(nt * 16 + lx) * N_;
        #pragma unroll
        for (int ks = 0; ks < 4; ++ks) {
            short8 bv = *(const short8*)(vrow + ks * 32 + quad * 8);
            oacc[nt] = __builtin_amdgcn_mfma_f32_16x16x32_bf16(ap[ks], bv, oacc[nt], 0, 0, 0);
        }
    }

    #pragma unroll
    for (int r = 0; r < 4; ++r) {
        const int il = w * 16 + quad * 4 + r;
        const int i = qb + il;
        const float inv = 1.0f / l4[r];
        const float ps = ps4[r];
        #pragma unroll
        for (int nt = 0; nt < 4; ++nt) {
            const int d = nt * 16 + lx;
            float o = oacc[nt][r];
            if (has_self)
                o = fmaf(ps, b2f((short)Vd[d * 72 + il]), o);
            ctx[((size_t)(b * N_) + i) * DM + h * DK_ + d] = f2b(o * inv);
        }
    }
}

__device__ __forceinline__
void fc_step(const unsigned short* Ac, const unsigned short* Bc,
             int wv, int mrow, int koff, floatx4 acc[2][4])
{
    short8 af[2], bf[4];
    #pragma unroll
    for (int t = 0; t < 2; ++t)
        af[t] = *(const short8*)&Ac[(t * 16 + mrow) * 32 + koff];
    #pragma unroll
    for (int t = 0; t < 4; ++t)
        bf[t] = *(const short8*)&Bc[(wv * 64 + t * 16 + mrow) * 32 + koff];
    #pragma unroll
    for (int mt = 0; mt < 2; ++mt)
        #pragma unroll
        for (int nt = 0; nt < 4; ++nt)
            acc[mt][nt] = __builtin_amdgcn_mfma_f32_16x16x32_bf16(
                af[mt], bf[nt], acc[mt][nt], 0, 0, 0);
}

__global__ __launch_bounds__(512)
void fc_ln_kernel(const unsigned short* __restrict__ A,
                  const unsigned short* __restrict__ W,
                  const float* __restrict__ bias,
                  const float* __restrict__ resid,
                  const float* __restrict__ g,
                  const float* __restrict__ bb,
                  float* __restrict__ out)
{
    __shared__ __align__(16) unsigned short As[2 * 32 * 32];
    __shared__ __align__(16) unsigned short Bs[2 * 512 * 32];
    __shared__ float lsum[32][8];
    __shared__ float lsq[32][8];

    const int tid  = threadIdx.x;
    const int lane = tid & 63;
    const int wv   = tid >> 6;
    const int m0   = blockIdx.x * 32;

    const int srow = tid >> 2;
    const int skq  = (tid & 3) * 8;
    const unsigned short* Ag = A + (size_t)(m0 + srow) * 512 + skq;
    const unsigned short* Bg = W + (size_t)srow * 512 + skq;

    const int mrow = lane & 15;
    const int koff = (lane >> 4) * 8;

    unsigned short* A0 = As;        unsigned short* A1 = As + 1024;
    unsigned short* B0 = Bs;        unsigned short* B1 = Bs + 16384;

#define FSTAGE(Ad, Bd, off)                                                    \
    do {                                                                       \
        if (tid < 128) GLD16(Ag + (off), &(Ad)[tid * 8]);                      \
        _Pragma("unroll")                                                      \
        for (int p = 0; p < 4; ++p)                                            \
            GLD16(Bg + (size_t)p * 128 * 512 + (off),                          \
                  &(Bd)[p * 4096 + tid * 8]);                                  \
    } while (0)

    floatx4 acc[2][4];
    #pragma unroll
    for (int i = 0; i < 2; ++i)
        #pragma unroll
        for (int j = 0; j < 4; ++j)
            acc[i][j] = (floatx4){0.f, 0.f, 0.f, 0.f};

    FSTAGE(A0, B0, 0);
    __syncthreads();

    #pragma unroll
    for (int kt = 0; kt < 512; kt += 64) {
        FSTAGE(A1, B1, kt + 32);
        fc_step(A0, B0, wv, mrow, koff, acc);
        __syncthreads();
        if (kt + 64 < 512)
            FSTAGE(A0, B0, kt + 64);
        fc_step(A1, B1, wv, mrow, koff, acc);
        __syncthreads();
    }
#undef FSTAGE

    const int quad = lane >> 4;
    const int lx   = lane & 15;
    float s[2][4], ss[2][4];
    #pragma unroll
    for (int mt = 0; mt < 2; ++mt)
        #pragma unroll
        for (int r = 0; r < 4; ++r) { s[mt][r] = 0.f; ss[mt][r] = 0.f; }

    #pragma unroll
    for (int mt = 0; mt < 2; ++mt)
        #pragma unroll
        for (int nt = 0; nt < 4; ++nt) {
            const int c = wv * 64 + nt * 16 + lx;
            const float bvv = bias[c];
            #pragma unroll
            for (int r = 0; r < 4; ++r) {
                const size_t row = (size_t)(m0 + mt * 16 + quad * 4 + r);
                float v = acc[mt][nt][r] + bvv + resid[row * 512 + c];
                acc[mt][nt][r] = v;
                s[mt][r] += v;
                ss[mt][r] = fmaf(v, v, ss[mt][r]);
            }
        }

    #pragma unroll
    for (int o = 1; o < 16; o <<= 1)
        #pragma unroll
        for (int mt = 0; mt < 2; ++mt)
            #pragma unroll
            for (int r = 0; r < 4; ++r) {
                s[mt][r]  += __shfl_xor(s[mt][r],  o, 64);
                ss[mt][r] += __shfl_xor(ss[mt][r], o, 64);
            }
    if (lx == 0) {
        #pragma unroll
        for (int mt = 0; mt < 2; ++mt)
            #pragma unroll
            for (int r = 0; r < 4; ++r) {
                lsum[mt * 16 + quad * 4 + r][wv] = s[mt][r];
                lsq [mt * 16 + quad * 4 + r][wv] = ss[mt][r];
            }
    }
    __syncthreads();

    #pragma unroll
    for (int mt = 0; mt < 2; ++mt)
        #pragma unroll
        for (int r = 0; r < 4; ++r) {
            const int rl = mt * 16 + quad * 4 + r;
            float ts = 0.f, tss = 0.f;
            #pragma unroll
            for (int u = 0; u < 8; ++u) { ts += lsum[rl][u]; tss += lsq[rl][u]; }
            const float mean = ts * (1.0f / DM);
            const float var  = tss * (1.0f / DM) - mean * mean;
            const float rstd = rsqrtf(var + 1e-6f);
            const size_t row = (size_t)(m0 + rl);
            #pragma unroll
            for (int nt = 0; nt < 4; ++nt) {
                const int c = wv * 64 + nt * 16 + lx;
                out[row * 512 + c] =
                    (acc[mt][nt][r] - mean) * rstd * g[c] + bb[c];
            }
        }
}

// ---------------------------------------------------------------------------
extern "C" void kernel_launch(void* const* d_in, const int* in_sizes, int n_in,
                              void* d_out, int out_size, void* d_ws, size_t ws_size,
                              hipStream_t stream)
{
    (void)in_sizes; (void)n_in; (void)out_size; (void)ws_size;
    const float* hidden = (const float*)d_in[0];
    const float* rpe    = (const float*)d_in[1];
    const float* Wq     = (const float*)d_in[2];
    const float* Wk     = (const float*)d_in[3];
    const float* Wv     = (const float*)d_in[4];
    const float* fc_w   = (const float*)d_in[5];
    const float* fc_b   = (const float*)d_in[6];
    const float* ln_g   = (const float*)d_in[7];
    const float* ln_b   = (const float*)d_in[8];
    float* out = (float*)d_out;
    char* ws = (char*)d_ws;

    const size_t MB = 1024 * 1024;
    unsigned short* hb  = (unsigned short*)(ws + 0 * MB);
    unsigned short* wq  = (unsigned short*)(ws + 8 * MB);
    unsigned short* wk  = (unsigned short*)(ws + 8 * MB + 512 * 1024);
    unsigned short* wv  = (unsigned short*)(ws + 9 * MB);
    unsigned short* wf  = (unsigned short*)(ws + 9 * MB + 512 * 1024);
    unsigned short* qB  = (unsigned short*)(ws + 16 * MB);
    unsigned short* kB  = (unsigned short*)(ws + 24 * MB);
    unsigned short* vtB = (unsigned short*)(ws + 32 * MB);
    unsigned short* cb  = (unsigned short*)(ws + 40 * MB);

    FusedArgs fa;
    fa.hidden = hidden; fa.rpe = rpe;
    fa.Wq = Wq; fa.Wk = Wk; fa.Wv = Wv; fa.fc_w = fc_w; fa.fc_b = fc_b;
    fa.ln_g = ln_g; fa.ln_b = ln_b; fa.out = out;
    fa.hb = hb; fa.wq = wq; fa.wk = wk; fa.wv = wv; fa.wf = wf;
    fa.qB = qB; fa.kB = kB; fa.vtB = vtB; fa.cb = cb;

    void* kargs[] = { (void*)&fa };
    hipError_t e = hipLaunchCooperativeKernel(
        (const void*)fused_all, dim3(256), dim3(512), kargs, 0, stream);

    if (e != hipSuccess) {
        // Fallback: proven round-2 four-kernel pipeline.
        CastArgs ca;
        ca.src[0] = hidden; ca.dst[0] = hb;
        ca.src[1] = Wq;     ca.dst[1] = wq;
        ca.src[2] = Wk;     ca.dst[2] = wk;
        ca.src[3] = Wv;     ca.dst[3] = wv;
        ca.src[4] = fc_w;   ca.dst[4] = wf;
        cast_bf16_kernel<<<dim3(2048 + 4 * 128), 256, 0, stream>>>(ca);
        qkv_gemm_kernel<<<dim3(64, 12), 256, 0, stream>>>(hb, wq, wk, wv,
                                                          qB, kB, vtB);
        attn_kernel<<<dim3(16, H_, B_), 256, 0, stream>>>(qB, kB, vtB, rpe, cb);
        fc_ln_kernel<<<dim3(256), 512, 0, stream>>>(cb, wf, fc_b, hidden,
                                                    ln_g, ln_b, out);
    }
}

// Round 5
// 403.807 us; speedup vs baseline: 1.6118x; 1.6118x over previous
//
#include <hip/hip_runtime.h>
#include <hip/hip_bf16.h>
#include <math.h>

#define B_  8
#define N_  1024
#define DM  512
#define H_  8
#define DK_ 64
#define ST  128

typedef __attribute__((ext_vector_type(8))) short short8;
typedef __attribute__((ext_vector_type(4))) float floatx4;

#define GLD16(gp, lp)                                                          \
    __builtin_amdgcn_global_load_lds(                                          \
        (const __attribute__((address_space(1))) void*)(gp),                   \
        (__attribute__((address_space(3))) void*)(lp), 16, 0, 0)

__device__ __forceinline__ float b2f(short u) {
    union { unsigned int i; float f; } c;
    c.i = ((unsigned int)(unsigned short)u) << 16;
    return c.f;
}
__device__ __forceinline__ unsigned short f2b(float f) {
    __hip_bfloat16 t = __float2bfloat16(f);
    return *(unsigned short*)&t;
}
__device__ __forceinline__ short8 cvt8(float4 x0, float4 x1) {
    short8 r;
    r[0] = (short)f2b(x0.x); r[1] = (short)f2b(x0.y);
    r[2] = (short)f2b(x0.z); r[3] = (short)f2b(x0.w);
    r[4] = (short)f2b(x1.x); r[5] = (short)f2b(x1.y);
    r[6] = (short)f2b(x1.z); r[7] = (short)f2b(x1.w);
    return r;
}

// ---------------------------------------------------------------------------
// Fused QKV GEMM reading fp32 inputs directly (cast folded into staging).
// 128x128 tile, BK=32, 256 threads (4 waves 2x2). Staging: fp32 global ->
// regs -> RNE bf16 -> ds_write_b128. Next K-step's loads issue during the
// current MFMA cluster (T14 split), hiding fp32 load latency under compute.
// Outputs bf16: q,k as [B,H,N,64]; v transposed [B,H,64,N].
// blockIdx.y in [0,12): y>>2 selects q/k/v, (y&3)*128 = n0.
// ---------------------------------------------------------------------------
__global__ __launch_bounds__(256)
void qkv_gemm_kernel(const float* __restrict__ A32,
                     const float* __restrict__ W0,
                     const float* __restrict__ W1,
                     const float* __restrict__ W2,
                     unsigned short* __restrict__ qo,
                     unsigned short* __restrict__ ko,
                     unsigned short* __restrict__ vto)
{
    __shared__ __align__(16) unsigned short As[128 * 32];
    __shared__ __align__(16) unsigned short Bs[128 * 32];

    const int tid  = threadIdx.x;
    const int lane = tid & 63;
    const int wave = tid >> 6;
    const int wm = wave >> 1, wn = wave & 1;
    const int by = blockIdx.y;
    const int sel = by >> 2;
    const float* W = (sel == 0) ? W0 : (sel == 1 ? W1 : W2);
    const int m0 = blockIdx.x * 128;
    const int n0 = (by & 3) * 128;

    const int srow = tid >> 2;            // 0..63
    const int skq  = (tid & 3) * 8;
    const float* Ag = A32 + (size_t)(m0 + srow) * 512 + skq;
    const float* Bg = W   + (size_t)(n0 + srow) * 512 + skq;
    const int mrow = lane & 15;
    const int koff = (lane >> 4) * 8;
    const int ldso = srow * 32 + skq;

    floatx4 acc[4][4];
    #pragma unroll
    for (int i = 0; i < 4; ++i)
        #pragma unroll
        for (int j = 0; j < 4; ++j)
            acc[i][j] = (floatx4){0.f, 0.f, 0.f, 0.f};

    float4 a0, a1, a2, a3, b0, b1, b2, b3;
#define LOADS(off)                                                             \
    do {                                                                       \
        a0 = *(const float4*)(Ag + (off));                                     \
        a1 = *(const float4*)(Ag + (off) + 4);                                 \
        a2 = *(const float4*)(Ag + 64 * 512 + (off));                          \
        a3 = *(const float4*)(Ag + 64 * 512 + (off) + 4);                      \
        b0 = *(const float4*)(Bg + (off));                                     \
        b1 = *(const float4*)(Bg + (off) + 4);                                 \
        b2 = *(const float4*)(Bg + 64 * 512 + (off));                          \
        b3 = *(const float4*)(Bg + 64 * 512 + (off) + 4);                      \
    } while (0)

    LOADS(0);
    for (int kt = 0; kt < 512; kt += 32) {
        __syncthreads();                       // prior compute done with LDS
        *(short8*)&As[ldso]        = cvt8(a0, a1);
        *(short8*)&As[2048 + ldso] = cvt8(a2, a3);
        *(short8*)&Bs[ldso]        = cvt8(b0, b1);
        *(short8*)&Bs[2048 + ldso] = cvt8(b2, b3);
        __syncthreads();
        if (kt + 32 < 512)
            LOADS(kt + 32);                    // issue early; hides under MFMA
        short8 af[4], bf[4];
        #pragma unroll
        for (int t = 0; t < 4; ++t) {
            af[t] = *(const short8*)&As[(wm * 64 + t * 16 + mrow) * 32 + koff];
            bf[t] = *(const short8*)&Bs[(wn * 64 + t * 16 + mrow) * 32 + koff];
        }
        #pragma unroll
        for (int mt = 0; mt < 4; ++mt)
            #pragma unroll
            for (int nt = 0; nt < 4; ++nt)
                acc[mt][nt] = __builtin_amdgcn_mfma_f32_16x16x32_bf16(
                    af[mt], bf[nt], acc[mt][nt], 0, 0, 0);
    }
#undef LOADS

    const int lx = lane & 15;
    const int rq = (lane >> 4) * 4;

    if (sel == 2) {
        // V transposed: [B,H,64,N] — r-direction is token-contiguous.
        #pragma unroll
        for (int mt = 0; mt < 4; ++mt) {
            const int mr = m0 + wm * 64 + mt * 16 + rq;
            const int bb = mr >> 10, tok = mr & 1023;
            #pragma unroll
            for (int nt = 0; nt < 4; ++nt) {
                const int c = n0 + wn * 64 + nt * 16 + lx;
                const int hh = c >> 6, d = c & 63;
                ushort4 pk;
                pk.x = f2b(acc[mt][nt][0]); pk.y = f2b(acc[mt][nt][1]);
                pk.z = f2b(acc[mt][nt][2]); pk.w = f2b(acc[mt][nt][3]);
                *(ushort4*)&vto[((size_t)(bb * H_ + hh) * DK_ + d) * N_ + tok] = pk;
            }
        }
    } else {
        unsigned short* O = (sel == 0) ? qo : ko;
        #pragma unroll
        for (int mt = 0; mt < 4; ++mt) {
            const int mr = m0 + wm * 64 + mt * 16 + rq;
            const int bb = mr >> 10, tok = mr & 1023;
            #pragma unroll
            for (int nt = 0; nt < 4; ++nt) {
                const int c = n0 + wn * 64 + nt * 16 + lx;
                const int hh = c >> 6, d = c & 63;
                unsigned short* p =
                    O + ((size_t)(bb * H_ + hh) * N_ + tok) * DK_ + d;
                #pragma unroll
                for (int r = 0; r < 4; ++r)
                    p[(size_t)r * DK_] = f2b(acc[mt][nt][r]);
            }
        }
    }
}

// ---------------------------------------------------------------------------
// Star-sparse MFMA attention (round-1 proven version) + piggybacked fc_w
// fp32->bf16 cast on 16 of 1024 blocks (consumed by fc_ln, ordered by the
// existing attn->fc_ln graph edge).
// ---------------------------------------------------------------------------
__global__ __launch_bounds__(256)
void attn_kernel(const unsigned short* __restrict__ qg,
                 const unsigned short* __restrict__ kg,
                 const unsigned short* __restrict__ vtg,
                 const float* __restrict__ rpe,
                 const float* __restrict__ fcw,
                 unsigned short* __restrict__ wf,
                 unsigned short* __restrict__ ctx)
{
    __shared__ __align__(16) unsigned short P[64 * 136];   // 17.4 KB
    __shared__ __align__(16) unsigned short Vd[64 * 72];   // 9.2 KB diag V

    const int tid  = threadIdx.x;

    // ---- side job: cast fc_w (512x512) on blocks (z==0,y==0) ----
    if (blockIdx.z == 0 && blockIdx.y == 0) {
        const int base = blockIdx.x * 256 + tid;           // 0..4095
        #pragma unroll
        for (int it = 0; it < 8; ++it) {
            const int i = (it * 4096 + base) * 8;
            float4 x0 = *(const float4*)&fcw[i];
            float4 x1 = *(const float4*)&fcw[i + 4];
            *(short8*)&wf[i] = cvt8(x0, x1);
        }
    }

    const int lane = tid & 63;
    const int w    = tid >> 6;
    const int lx   = lane & 15;
    const int quad = lane >> 4;
    const int qb = blockIdx.x * 64;
    const int h  = blockIdx.y, b = blockIdx.z;
    const int bh = b * H_ + h;
    const unsigned short* qh  = qg  + (size_t)bh * N_ * DK_;
    const unsigned short* kh  = kg  + (size_t)bh * N_ * DK_;
    const unsigned short* vth = vtg + (size_t)bh * DK_ * N_;
    const float* rp = rpe + ((size_t)bh * N_ + qb) * N_;   // local row i -> rp[i*N_]
    const bool has_self = (qb >= ST);

    // ---- cooperative stage of diagonal V tile: Vd[d][tok_local] ----
    if (has_self) {
        const int d = tid >> 2, t16 = (tid & 3) * 16;
        const unsigned short* vs = vth + (size_t)d * N_ + qb + t16;
        *(short8*)&Vd[d * 72 + t16]     = *(const short8*)vs;
        *(short8*)&Vd[d * 72 + t16 + 8] = *(const short8*)(vs + 8);
    }

    // ---- self-loop score: lane covers row (w*16+lx), d-quarter quad ----
    float sself = -1e30f;
    if (has_self) {
        const int i = qb + w * 16 + lx;
        const unsigned short* qr = qh + (size_t)i * DK_ + quad * 16;
        const unsigned short* kr = kh + (size_t)i * DK_ + quad * 16;
        short8 q0 = *(const short8*)qr, q1 = *(const short8*)(qr + 8);
        short8 k0 = *(const short8*)kr, k1 = *(const short8*)(kr + 8);
        float dot = 0.f;
        #pragma unroll
        for (int j = 0; j < 8; ++j) {
            dot = fmaf(b2f(q0[j]), b2f(k0[j]), dot);
            dot = fmaf(b2f(q1[j]), b2f(k1[j]), dot);
        }
        dot += __shfl_xor(dot, 16, 64);
        dot += __shfl_xor(dot, 32, 64);
        const float rd = rp[(size_t)(w * 16 + lx) * N_ + (qb + w * 16 + lx)];
        sself = (dot + rd) * 0.125f;
    }

    // ---- rpe prefetch: lane covers rows (w*16+quad*4+r), cols nt*16+lx ----
    float rv[4][8];
    {
        const float* rbase = rp + (size_t)(w * 16 + quad * 4) * N_ + lx;
        #pragma unroll
        for (int r = 0; r < 4; ++r)
            #pragma unroll
            for (int nt = 0; nt < 8; ++nt)
                rv[r][nt] = rbase[(size_t)r * N_ + nt * 16];
    }

    // ---- S = Q*K^T (A,B frags straight from global) ----
    short8 aq[2];
    {
        const unsigned short* qrow =
            qh + (size_t)(qb + w * 16 + lx) * DK_ + quad * 8;
        aq[0] = *(const short8*)qrow;
        aq[1] = *(const short8*)(qrow + 32);
    }
    floatx4 sacc[8];
    #pragma unroll
    for (int nt = 0; nt < 8; ++nt) sacc[nt] = (floatx4){0.f, 0.f, 0.f, 0.f};
    #pragma unroll
    for (int nt = 0; nt < 8; ++nt) {
        const unsigned short* krow =
            kh + (size_t)(nt * 16 + lx) * DK_ + quad * 8;
        short8 b0 = *(const short8*)krow;
        short8 b1 = *(const short8*)(krow + 32);
        sacc[nt] = __builtin_amdgcn_mfma_f32_16x16x32_bf16(aq[0], b0, sacc[nt], 0, 0, 0);
        sacc[nt] = __builtin_amdgcn_mfma_f32_16x16x32_bf16(aq[1], b1, sacc[nt], 0, 0, 0);
    }

    // ---- softmax (fully in-wave; rows = w*16 + quad*4 + r) ----
    float l4[4], ps4[4];
    #pragma unroll
    for (int r = 0; r < 4; ++r) {
        float sv[8];
        float mx = -1e30f;
        #pragma unroll
        for (int nt = 0; nt < 8; ++nt) {
            sv[nt] = (sacc[nt][r] + rv[r][nt]) * 0.125f;
            mx = fmaxf(mx, sv[nt]);
        }
        #pragma unroll
        for (int o = 1; o < 16; o <<= 1)
            mx = fmaxf(mx, __shfl_xor(mx, o, 64));
        const float ss = __shfl(sself, quad * 4 + r, 64);
        mx = fmaxf(mx, ss);
        float sum = 0.f;
        #pragma unroll
        for (int nt = 0; nt < 8; ++nt) {
            sv[nt] = __expf(sv[nt] - mx);
            sum += sv[nt];
        }
        #pragma unroll
        for (int o = 1; o < 16; o <<= 1)
            sum += __shfl_xor(sum, o, 64);
        const float ps = has_self ? __expf(ss - mx) : 0.f;
        l4[r] = sum + ps;
        ps4[r] = ps;
        const int row = w * 16 + quad * 4 + r;
        #pragma unroll
        for (int nt = 0; nt < 8; ++nt)
            P[row * 136 + nt * 16 + lx] = f2b(sv[nt]);
    }
    __syncthreads();

    // ---- O = P*V (A frags from LDS, B frags from global vT) ----
    short8 ap[4];
    #pragma unroll
    for (int ks = 0; ks < 4; ++ks)
        ap[ks] = *(const short8*)&P[(w * 16 + lx) * 136 + ks * 32 + quad * 8];
    floatx4 oacc[4];
    #pragma unroll
    for (int nt = 0; nt < 4; ++nt) oacc[nt] = (floatx4){0.f, 0.f, 0.f, 0.f};
    #pragma unroll
    for (int nt = 0; nt < 4; ++nt) {
        const unsigned short* vrow = vth + (size_t)(nt * 16 + lx) * N_;
        #pragma unroll
        for (int ks = 0; ks < 4; ++ks) {
            short8 bv = *(const short8*)(vrow + ks * 32 + quad * 8);
            oacc[nt] = __builtin_amdgcn_mfma_f32_16x16x32_bf16(ap[ks], bv, oacc[nt], 0, 0, 0);
        }
    }

    // ---- self V (from LDS) + normalize + store ctx bf16 [B*N][512] ----
    #pragma unroll
    for (int r = 0; r < 4; ++r) {
        const int il = w * 16 + quad * 4 + r;
        const int i = qb + il;
        const float inv = 1.0f / l4[r];
        const float ps = ps4[r];
        #pragma unroll
        for (int nt = 0; nt < 4; ++nt) {
            const int d = nt * 16 + lx;
            float o = oacc[nt][r];
            if (has_self)
                o = fmaf(ps, b2f((short)Vd[d * 72 + il]), o);
            ctx[((size_t)(b * N_) + i) * DM + h * DK_ + d] = f2b(o * inv);
        }
    }
}

// ---------------------------------------------------------------------------
// Fused FC + residual + LayerNorm (round-2 proven version).
// ---------------------------------------------------------------------------
__device__ __forceinline__
void fc_step(const unsigned short* Ac, const unsigned short* Bc,
             int wv, int mrow, int koff, floatx4 acc[2][4])
{
    short8 af[2], bf[4];
    #pragma unroll
    for (int t = 0; t < 2; ++t)
        af[t] = *(const short8*)&Ac[(t * 16 + mrow) * 32 + koff];
    #pragma unroll
    for (int t = 0; t < 4; ++t)
        bf[t] = *(const short8*)&Bc[(wv * 64 + t * 16 + mrow) * 32 + koff];
    #pragma unroll
    for (int mt = 0; mt < 2; ++mt)
        #pragma unroll
        for (int nt = 0; nt < 4; ++nt)
            acc[mt][nt] = __builtin_amdgcn_mfma_f32_16x16x32_bf16(
                af[mt], bf[nt], acc[mt][nt], 0, 0, 0);
}

__global__ __launch_bounds__(512)
void fc_ln_kernel(const unsigned short* __restrict__ A,   // ctx bf16 [8192][512]
                  const unsigned short* __restrict__ W,   // wf bf16 [512][512]
                  const float* __restrict__ bias,
                  const float* __restrict__ resid,
                  const float* __restrict__ g,
                  const float* __restrict__ bb,
                  float* __restrict__ out)
{
    __shared__ __align__(16) unsigned short As[2 * 32 * 32];
    __shared__ __align__(16) unsigned short Bs[2 * 512 * 32];
    __shared__ float lsum[32][8];
    __shared__ float lsq[32][8];

    const int tid  = threadIdx.x;
    const int lane = tid & 63;
    const int wv   = tid >> 6;
    const int m0   = blockIdx.x * 32;

    const int srow = tid >> 2;
    const int skq  = (tid & 3) * 8;
    const unsigned short* Ag = A + (size_t)(m0 + srow) * 512 + skq;
    const unsigned short* Bg = W + (size_t)srow * 512 + skq;

    const int mrow = lane & 15;
    const int koff = (lane >> 4) * 8;

    unsigned short* A0 = As;        unsigned short* A1 = As + 1024;
    unsigned short* B0 = Bs;        unsigned short* B1 = Bs + 16384;

#define FSTAGE(Ad, Bd, off)                                                    \
    do {                                                                       \
        if (tid < 128) GLD16(Ag + (off), &(Ad)[tid * 8]);                      \
        _Pragma("unroll")                                                      \
        for (int p = 0; p < 4; ++p)                                            \
            GLD16(Bg + (size_t)p * 128 * 512 + (off),                          \
                  &(Bd)[p * 4096 + tid * 8]);                                  \
    } while (0)

    floatx4 acc[2][4];
    #pragma unroll
    for (int i = 0; i < 2; ++i)
        #pragma unroll
        for (int j = 0; j < 4; ++j)
            acc[i][j] = (floatx4){0.f, 0.f, 0.f, 0.f};

    FSTAGE(A0, B0, 0);
    __syncthreads();

    #pragma unroll
    for (int kt = 0; kt < 512; kt += 64) {
        FSTAGE(A1, B1, kt + 32);
        fc_step(A0, B0, wv, mrow, koff, acc);
        __syncthreads();
        if (kt + 64 < 512)
            FSTAGE(A0, B0, kt + 64);
        fc_step(A1, B1, wv, mrow, koff, acc);
        __syncthreads();
    }
#undef FSTAGE

    const int quad = lane >> 4;
    const int lx   = lane & 15;
    float s[2][4], ss[2][4];
    #pragma unroll
    for (int mt = 0; mt < 2; ++mt)
        #pragma unroll
        for (int r = 0; r < 4; ++r) { s[mt][r] = 0.f; ss[mt][r] = 0.f; }

    #pragma unroll
    for (int mt = 0; mt < 2; ++mt)
        #pragma unroll
        for (int nt = 0; nt < 4; ++nt) {
            const int c = wv * 64 + nt * 16 + lx;
            const float bvv = bias[c];
            #pragma unroll
            for (int r = 0; r < 4; ++r) {
                const size_t row = (size_t)(m0 + mt * 16 + quad * 4 + r);
                float v = acc[mt][nt][r] + bvv + resid[row * 512 + c];
                acc[mt][nt][r] = v;
                s[mt][r] += v;
                ss[mt][r] = fmaf(v, v, ss[mt][r]);
            }
        }

    #pragma unroll
    for (int o = 1; o < 16; o <<= 1)
        #pragma unroll
        for (int mt = 0; mt < 2; ++mt)
            #pragma unroll
            for (int r = 0; r < 4; ++r) {
                s[mt][r]  += __shfl_xor(s[mt][r],  o, 64);
                ss[mt][r] += __shfl_xor(ss[mt][r], o, 64);
            }
    if (lx == 0) {
        #pragma unroll
        for (int mt = 0; mt < 2; ++mt)
            #pragma unroll
            for (int r = 0; r < 4; ++r) {
                lsum[mt * 16 + quad * 4 + r][wv] = s[mt][r];
                lsq [mt * 16 + quad * 4 + r][wv] = ss[mt][r];
            }
    }
    __syncthreads();

    #pragma unroll
    for (int mt = 0; mt < 2; ++mt)
        #pragma unroll
        for (int r = 0; r < 4; ++r) {
            const int rl = mt * 16 + quad * 4 + r;
            float ts = 0.f, tss = 0.f;
            #pragma unroll
            for (int u = 0; u < 8; ++u) { ts += lsum[rl][u]; tss += lsq[rl][u]; }
            const float mean = ts * (1.0f / DM);
            const float var  = tss * (1.0f / DM) - mean * mean;
            const float rstd = rsqrtf(var + 1e-6f);
            const size_t row = (size_t)(m0 + rl);
            #pragma unroll
            for (int nt = 0; nt < 4; ++nt) {
                const int c = wv * 64 + nt * 16 + lx;
                out[row * 512 + c] =
                    (acc[mt][nt][r] - mean) * rstd * g[c] + bb[c];
            }
        }
}

// ---------------------------------------------------------------------------
extern "C" void kernel_launch(void* const* d_in, const int* in_sizes, int n_in,
                              void* d_out, int out_size, void* d_ws, size_t ws_size,
                              hipStream_t stream)
{
    (void)in_sizes; (void)n_in; (void)out_size; (void)ws_size;
    const float* hidden = (const float*)d_in[0];
    const float* rpe    = (const float*)d_in[1];
    const float* Wq     = (const float*)d_in[2];
    const float* Wk     = (const float*)d_in[3];
    const float* Wv     = (const float*)d_in[4];
    const float* fc_w   = (const float*)d_in[5];
    const float* fc_b   = (const float*)d_in[6];
    const float* ln_g   = (const float*)d_in[7];
    const float* ln_b   = (const float*)d_in[8];
    float* out = (float*)d_out;
    char* ws = (char*)d_ws;

    const size_t MB = 1024 * 1024;
    unsigned short* wf  = (unsigned short*)(ws + 9 * MB + 512 * 1024);
    unsigned short* qB  = (unsigned short*)(ws + 16 * MB);   // 8 MB [B,H,N,64]
    unsigned short* kB  = (unsigned short*)(ws + 24 * MB);   // 8 MB [B,H,N,64]
    unsigned short* vtB = (unsigned short*)(ws + 32 * MB);   // 8 MB [B,H,64,N]
    unsigned short* cb  = (unsigned short*)(ws + 40 * MB);   // 8 MB ctx

    qkv_gemm_kernel<<<dim3(64, 12), 256, 0, stream>>>(hidden, Wq, Wk, Wv,
                                                      qB, kB, vtB);
    attn_kernel<<<dim3(16, H_, B_), 256, 0, stream>>>(qB, kB, vtB, rpe,
                                                      fc_w, wf, cb);
    fc_ln_kernel<<<dim3(256), 512, 0, stream>>>(cb, wf, fc_b, hidden,
                                                ln_g, ln_b, out);
}

// Round 6
// 387.119 us; speedup vs baseline: 1.6812x; 1.0431x over previous
//
#include <hip/hip_runtime.h>
#include <hip/hip_bf16.h>
#include <math.h>

#define B_  8
#define N_  1024
#define DM  512
#define H_  8
#define DK_ 64
#define ST  128

typedef __attribute__((ext_vector_type(8))) short short8;
typedef __attribute__((ext_vector_type(4))) float floatx4;

#define GLD16(gp, lp)                                                          \
    __builtin_amdgcn_global_load_lds(                                          \
        (const __attribute__((address_space(1))) void*)(gp),                   \
        (__attribute__((address_space(3))) void*)(lp), 16, 0, 0)

__device__ __forceinline__ float b2f(short u) {
    union { unsigned int i; float f; } c;
    c.i = ((unsigned int)(unsigned short)u) << 16;
    return c.f;
}
__device__ __forceinline__ unsigned short f2b(float f) {
    __hip_bfloat16 t = __float2bfloat16(f);
    return *(unsigned short*)&t;
}

// ---------------------------------------------------------------------------
// Cast fp32 -> bf16 (RNE). Flat grid: blocks [0,2048) -> hidden,
// then 4 x 128 blocks for the 512x512 weights. Exact sizes, no tail.
// ---------------------------------------------------------------------------
struct CastArgs {
    const float* src[5];
    unsigned short* dst[5];
};

__global__ __launch_bounds__(256)
void cast_bf16_kernel(CastArgs a)
{
    const int bx = blockIdx.x;
    int j, base;
    if (bx < 2048) { j = 0; base = bx; }
    else { const int r = bx - 2048; j = 1 + (r >> 7); base = r & 127; }
    const float* __restrict__ s = a.src[j];
    unsigned short* __restrict__ d = a.dst[j];
    const int i = (base * 256 + threadIdx.x) * 8;
    float4 x0 = *(const float4*)&s[i];
    float4 x1 = *(const float4*)&s[i + 4];
    ushort4 o0, o1;
    o0.x = f2b(x0.x); o0.y = f2b(x0.y); o0.z = f2b(x0.z); o0.w = f2b(x0.w);
    o1.x = f2b(x1.x); o1.y = f2b(x1.y); o1.z = f2b(x1.z); o1.w = f2b(x1.w);
    *(ushort4*)&d[i] = o0;
    *(ushort4*)&d[i + 4] = o1;
}

// ---------------------------------------------------------------------------
// MFMA GEMM core: 128x128 tile, BK=64, 256 threads (4 waves 2x2), bf16 in.
// Half the barrier/drain points of BK=32 (m233: stage+drain dominates the
// 2-barrier structure). [128][64] LDS has 128B row stride -> 16-way bank
// conflict if linear; fixed per rule 21: linear global_load_lds dest +
// pre-swizzled global source k-offset + matching XOR on ds_read address.
// Swizzle: col8_phys = col8_logical ^ (row & 7); residual aliasing 2-way
// (free, m136). Accumulation order is k-ascending, bit-identical to BK=32.
// ---------------------------------------------------------------------------
__device__ __forceinline__
void gemm_core(const unsigned short* __restrict__ A,
               const unsigned short* __restrict__ W,
               int m0, int n0, unsigned short* As, unsigned short* Bs,
               floatx4 acc[4][4])
{
    const int tid  = threadIdx.x;
    const int lane = tid & 63;
    const int wave = tid >> 6;
    const int wm = wave >> 1, wn = wave & 1;
    const int srow = tid >> 3;                       // 0..31
    const int skq  = (((tid >> 3) ^ tid) & 7) * 8;   // swizzled k-offset
    const unsigned short* Ag = A + (size_t)(m0 + srow) * 512 + skq;
    const unsigned short* Bg = W + (size_t)(n0 + srow) * 512 + skq;
    const int mrow = lane & 15;
    const int koff = (lane >> 4) * 8;
    const int sx   = (lane & 7) * 8;                 // read-side XOR

    for (int kt = 0; kt < 512; kt += 64) {
        __syncthreads();
        #pragma unroll
        for (int r = 0; r < 4; ++r) {
            GLD16(Ag + (size_t)r * 32 * 512 + kt, &As[r * 2048 + tid * 8]);
            GLD16(Bg + (size_t)r * 32 * 512 + kt, &Bs[r * 2048 + tid * 8]);
        }
        __syncthreads();
        #pragma unroll
        for (int kk = 0; kk < 2; ++kk) {
            short8 af[4], bf[4];
            #pragma unroll
            for (int t = 0; t < 4; ++t) {
                af[t] = *(const short8*)
                    &As[((wm * 64 + t * 16 + mrow) * 64 + kk * 32 + koff) ^ sx];
                bf[t] = *(const short8*)
                    &Bs[((wn * 64 + t * 16 + mrow) * 64 + kk * 32 + koff) ^ sx];
            }
            #pragma unroll
            for (int mt = 0; mt < 4; ++mt)
                #pragma unroll
                for (int nt = 0; nt < 4; ++nt)
                    acc[mt][nt] = __builtin_amdgcn_mfma_f32_16x16x32_bf16(
                        af[mt], bf[nt], acc[mt][nt], 0, 0, 0);
        }
    }
}

// ---------------------------------------------------------------------------
// Fused QKV GEMM. Outputs bf16: q,k as [B,H,N,64]; v transposed [B,H,64,N].
// blockIdx.y in [0,12): y>>2 selects q/k/v, (y&3)*128 = n0.
// ---------------------------------------------------------------------------
__global__ __launch_bounds__(256)
void qkv_gemm_kernel(const unsigned short* __restrict__ A,
                     const unsigned short* __restrict__ W0,
                     const unsigned short* __restrict__ W1,
                     const unsigned short* __restrict__ W2,
                     unsigned short* __restrict__ qo,
                     unsigned short* __restrict__ ko,
                     unsigned short* __restrict__ vto)
{
    __shared__ __align__(16) unsigned short As[128 * 64];   // 16 KB
    __shared__ __align__(16) unsigned short Bs[128 * 64];   // 16 KB
    const int by = blockIdx.y;
    const int sel = by >> 2;
    const unsigned short* W = (sel == 0) ? W0 : (sel == 1 ? W1 : W2);
    const int m0 = blockIdx.x * 128;
    const int n0 = (by & 3) * 128;

    floatx4 acc[4][4];
    #pragma unroll
    for (int i = 0; i < 4; ++i)
        #pragma unroll
        for (int j = 0; j < 4; ++j)
            acc[i][j] = (floatx4){0.f, 0.f, 0.f, 0.f};

    gemm_core(A, W, m0, n0, As, Bs, acc);

    const int lane = threadIdx.x & 63;
    const int wave = threadIdx.x >> 6;
    const int wm = wave >> 1, wn = wave & 1;
    const int lx = lane & 15;
    const int rq = (lane >> 4) * 4;

    if (sel == 2) {
        // V transposed: [B,H,64,N] — r-direction is token-contiguous.
        #pragma unroll
        for (int mt = 0; mt < 4; ++mt) {
            const int mrow = m0 + wm * 64 + mt * 16 + rq;
            const int bb = mrow >> 10, tok = mrow & 1023;
            #pragma unroll
            for (int nt = 0; nt < 4; ++nt) {
                const int c = n0 + wn * 64 + nt * 16 + lx;
                const int hh = c >> 6, d = c & 63;
                ushort4 pk;
                pk.x = f2b(acc[mt][nt][0]); pk.y = f2b(acc[mt][nt][1]);
                pk.z = f2b(acc[mt][nt][2]); pk.w = f2b(acc[mt][nt][3]);
                *(ushort4*)&vto[((size_t)(bb * H_ + hh) * DK_ + d) * N_ + tok] = pk;
            }
        }
    } else {
        unsigned short* O = (sel == 0) ? qo : ko;
        #pragma unroll
        for (int mt = 0; mt < 4; ++mt) {
            const int mrow = m0 + wm * 64 + mt * 16 + rq;
            const int bb = mrow >> 10, tok = mrow & 1023;
            #pragma unroll
            for (int nt = 0; nt < 4; ++nt) {
                const int c = n0 + wn * 64 + nt * 16 + lx;
                const int hh = c >> 6, d = c & 63;
                unsigned short* p =
                    O + ((size_t)(bb * H_ + hh) * N_ + tok) * DK_ + d;
                #pragma unroll
                for (int r = 0; r < 4; ++r)
                    p[(size_t)r * DK_] = f2b(acc[mt][nt][r]);
            }
        }
    }
}

// ---------------------------------------------------------------------------
// Star-sparse MFMA attention (round-1 proven version, unchanged).
// ---------------------------------------------------------------------------
__global__ __launch_bounds__(256)
void attn_kernel(const unsigned short* __restrict__ qg,
                 const unsigned short* __restrict__ kg,
                 const unsigned short* __restrict__ vtg,
                 const float* __restrict__ rpe,
                 unsigned short* __restrict__ ctx)
{
    __shared__ __align__(16) unsigned short P[64 * 136];   // 17.4 KB
    __shared__ __align__(16) unsigned short Vd[64 * 72];   // 9.2 KB diag V

    const int tid  = threadIdx.x;
    const int lane = tid & 63;
    const int w    = tid >> 6;
    const int lx   = lane & 15;
    const int quad = lane >> 4;
    const int qb = blockIdx.x * 64;
    const int h  = blockIdx.y, b = blockIdx.z;
    const int bh = b * H_ + h;
    const unsigned short* qh  = qg  + (size_t)bh * N_ * DK_;
    const unsigned short* kh  = kg  + (size_t)bh * N_ * DK_;
    const unsigned short* vth = vtg + (size_t)bh * DK_ * N_;
    const float* rp = rpe + ((size_t)bh * N_ + qb) * N_;   // local row i -> rp[i*N_]
    const bool has_self = (qb >= ST);

    // ---- cooperative stage of diagonal V tile: Vd[d][tok_local] ----
    if (has_self) {
        const int d = tid >> 2, t16 = (tid & 3) * 16;
        const unsigned short* vs = vth + (size_t)d * N_ + qb + t16;
        *(short8*)&Vd[d * 72 + t16]     = *(const short8*)vs;
        *(short8*)&Vd[d * 72 + t16 + 8] = *(const short8*)(vs + 8);
    }

    // ---- self-loop score: lane covers row (w*16+lx), d-quarter quad ----
    float sself = -1e30f;
    if (has_self) {
        const int i = qb + w * 16 + lx;
        const unsigned short* qr = qh + (size_t)i * DK_ + quad * 16;
        const unsigned short* kr = kh + (size_t)i * DK_ + quad * 16;
        short8 q0 = *(const short8*)qr, q1 = *(const short8*)(qr + 8);
        short8 k0 = *(const short8*)kr, k1 = *(const short8*)(kr + 8);
        float dot = 0.f;
        #pragma unroll
        for (int j = 0; j < 8; ++j) {
            dot = fmaf(b2f(q0[j]), b2f(k0[j]), dot);
            dot = fmaf(b2f(q1[j]), b2f(k1[j]), dot);
        }
        dot += __shfl_xor(dot, 16, 64);
        dot += __shfl_xor(dot, 32, 64);
        const float rd = rp[(size_t)(w * 16 + lx) * N_ + (qb + w * 16 + lx)];
        sself = (dot + rd) * 0.125f;
    }

    // ---- rpe prefetch: lane covers rows (w*16+quad*4+r), cols nt*16+lx ----
    float rv[4][8];
    {
        const float* rbase = rp + (size_t)(w * 16 + quad * 4) * N_ + lx;
        #pragma unroll
        for (int r = 0; r < 4; ++r)
            #pragma unroll
            for (int nt = 0; nt < 8; ++nt)
                rv[r][nt] = rbase[(size_t)r * N_ + nt * 16];
    }

    // ---- S = Q*K^T (A,B frags straight from global) ----
    short8 aq[2];
    {
        const unsigned short* qrow =
            qh + (size_t)(qb + w * 16 + lx) * DK_ + quad * 8;
        aq[0] = *(const short8*)qrow;
        aq[1] = *(const short8*)(qrow + 32);
    }
    floatx4 sacc[8];
    #pragma unroll
    for (int nt = 0; nt < 8; ++nt) sacc[nt] = (floatx4){0.f, 0.f, 0.f, 0.f};
    #pragma unroll
    for (int nt = 0; nt < 8; ++nt) {
        const unsigned short* krow =
            kh + (size_t)(nt * 16 + lx) * DK_ + quad * 8;
        short8 b0 = *(const short8*)krow;
        short8 b1 = *(const short8*)(krow + 32);
        sacc[nt] = __builtin_amdgcn_mfma_f32_16x16x32_bf16(aq[0], b0, sacc[nt], 0, 0, 0);
        sacc[nt] = __builtin_amdgcn_mfma_f32_16x16x32_bf16(aq[1], b1, sacc[nt], 0, 0, 0);
    }

    // ---- softmax (fully in-wave; rows = w*16 + quad*4 + r) ----
    float l4[4], ps4[4];
    #pragma unroll
    for (int r = 0; r < 4; ++r) {
        float sv[8];
        float mx = -1e30f;
        #pragma unroll
        for (int nt = 0; nt < 8; ++nt) {
            sv[nt] = (sacc[nt][r] + rv[r][nt]) * 0.125f;
            mx = fmaxf(mx, sv[nt]);
        }
        #pragma unroll
        for (int o = 1; o < 16; o <<= 1)
            mx = fmaxf(mx, __shfl_xor(mx, o, 64));
        const float ss = __shfl(sself, quad * 4 + r, 64);
        mx = fmaxf(mx, ss);
        float sum = 0.f;
        #pragma unroll
        for (int nt = 0; nt < 8; ++nt) {
            sv[nt] = __expf(sv[nt] - mx);
            sum += sv[nt];
        }
        #pragma unroll
        for (int o = 1; o < 16; o <<= 1)
            sum += __shfl_xor(sum, o, 64);
        const float ps = has_self ? __expf(ss - mx) : 0.f;
        l4[r] = sum + ps;
        ps4[r] = ps;
        const int row = w * 16 + quad * 4 + r;
        #pragma unroll
        for (int nt = 0; nt < 8; ++nt)
            P[row * 136 + nt * 16 + lx] = f2b(sv[nt]);
    }
    __syncthreads();

    // ---- O = P*V (A frags from LDS, B frags from global vT) ----
    short8 ap[4];
    #pragma unroll
    for (int ks = 0; ks < 4; ++ks)
        ap[ks] = *(const short8*)&P[(w * 16 + lx) * 136 + ks * 32 + quad * 8];
    floatx4 oacc[4];
    #pragma unroll
    for (int nt = 0; nt < 4; ++nt) oacc[nt] = (floatx4){0.f, 0.f, 0.f, 0.f};
    #pragma unroll
    for (int nt = 0; nt < 4; ++nt) {
        const unsigned short* vrow = vth + (size_t)(nt * 16 + lx) * N_;
        #pragma unroll
        for (int ks = 0; ks < 4; ++ks) {
            short8 bv = *(const short8*)(vrow + ks * 32 + quad * 8);
            oacc[nt] = __builtin_amdgcn_mfma_f32_16x16x32_bf16(ap[ks], bv, oacc[nt], 0, 0, 0);
        }
    }

    // ---- self V (from LDS) + normalize + store ctx bf16 [B*N][512] ----
    #pragma unroll
    for (int r = 0; r < 4; ++r) {
        const int il = w * 16 + quad * 4 + r;
        const int i = qb + il;
        const float inv = 1.0f / l4[r];
        const float ps = ps4[r];
        #pragma unroll
        for (int nt = 0; nt < 4; ++nt) {
            const int d = nt * 16 + lx;
            float o = oacc[nt][r];
            if (has_self)
                o = fmaf(ps, b2f((short)Vd[d * 72 + il]), o);
            ctx[((size_t)(b * N_) + i) * DM + h * DK_ + d] = f2b(o * inv);
        }
    }
}

// ---------------------------------------------------------------------------
// Fused FC + residual + LayerNorm. Block = 32 tokens x all 512 cols,
// 512 threads (8 waves, wave wv owns cols wv*64). BK=64: 8 K-iters, half
// the barrier/drain points (fully exposed at 1 block/CU). Same swizzled
// LDS scheme as gemm_core. LN fused as in round 2.
// ---------------------------------------------------------------------------
__global__ __launch_bounds__(512)
void fc_ln_kernel(const unsigned short* __restrict__ A,   // ctx bf16 [8192][512]
                  const unsigned short* __restrict__ W,   // fc_w bf16 [512][512]
                  const float* __restrict__ bias,
                  const float* __restrict__ resid,
                  const float* __restrict__ g,
                  const float* __restrict__ bb,
                  float* __restrict__ out)
{
    __shared__ __align__(16) unsigned short As[32 * 64];    // 4 KB
    __shared__ __align__(16) unsigned short Bs[512 * 64];   // 64 KB
    __shared__ float lsum[32][8];
    __shared__ float lsq[32][8];

    const int tid  = threadIdx.x;
    const int lane = tid & 63;
    const int wv   = tid >> 6;            // 0..7 -> col block wv*64
    const int m0   = blockIdx.x * 32;

    const int srow = tid >> 3;                       // 0..63
    const int skq  = (((tid >> 3) ^ tid) & 7) * 8;   // swizzled k-offset
    const unsigned short* Ag = A + (size_t)(m0 + (srow & 31)) * 512 + skq;
    const unsigned short* Bg = W + (size_t)srow * 512 + skq;

    const int mrow = lane & 15;
    const int koff = (lane >> 4) * 8;
    const int sx   = (lane & 7) * 8;

    floatx4 acc[2][4];
    #pragma unroll
    for (int i = 0; i < 2; ++i)
        #pragma unroll
        for (int j = 0; j < 4; ++j)
            acc[i][j] = (floatx4){0.f, 0.f, 0.f, 0.f};

    for (int kt = 0; kt < 512; kt += 64) {
        __syncthreads();
        if (tid < 256)
            GLD16(Ag + kt, &As[tid * 8]);
        #pragma unroll
        for (int r = 0; r < 8; ++r)
            GLD16(Bg + (size_t)r * 64 * 512 + kt, &Bs[r * 4096 + tid * 8]);
        __syncthreads();
        #pragma unroll
        for (int kk = 0; kk < 2; ++kk) {
            short8 af[2], bf[4];
            #pragma unroll
            for (int t = 0; t < 2; ++t)
                af[t] = *(const short8*)
                    &As[((t * 16 + mrow) * 64 + kk * 32 + koff) ^ sx];
            #pragma unroll
            for (int t = 0; t < 4; ++t)
                bf[t] = *(const short8*)
                    &Bs[((wv * 64 + t * 16 + mrow) * 64 + kk * 32 + koff) ^ sx];
            #pragma unroll
            for (int mt = 0; mt < 2; ++mt)
                #pragma unroll
                for (int nt = 0; nt < 4; ++nt)
                    acc[mt][nt] = __builtin_amdgcn_mfma_f32_16x16x32_bf16(
                        af[mt], bf[nt], acc[mt][nt], 0, 0, 0);
        }
    }

    // ---- bias + residual, in-register row partial sums ----
    const int quad = lane >> 4;
    const int lx   = lane & 15;
    float s[2][4], ss[2][4];
    #pragma unroll
    for (int mt = 0; mt < 2; ++mt)
        #pragma unroll
        for (int r = 0; r < 4; ++r) { s[mt][r] = 0.f; ss[mt][r] = 0.f; }

    #pragma unroll
    for (int mt = 0; mt < 2; ++mt)
        #pragma unroll
        for (int nt = 0; nt < 4; ++nt) {
            const int c = wv * 64 + nt * 16 + lx;
            const float bvv = bias[c];
            #pragma unroll
            for (int r = 0; r < 4; ++r) {
                const size_t row = (size_t)(m0 + mt * 16 + quad * 4 + r);
                float v = acc[mt][nt][r] + bvv + resid[row * 512 + c];
                acc[mt][nt][r] = v;
                s[mt][r] += v;
                ss[mt][r] = fmaf(v, v, ss[mt][r]);
            }
        }

    // reduce over the 16 lanes sharing a row (lx bits)
    #pragma unroll
    for (int o = 1; o < 16; o <<= 1)
        #pragma unroll
        for (int mt = 0; mt < 2; ++mt)
            #pragma unroll
            for (int r = 0; r < 4; ++r) {
                s[mt][r]  += __shfl_xor(s[mt][r],  o, 64);
                ss[mt][r] += __shfl_xor(ss[mt][r], o, 64);
            }
    if (lx == 0) {
        #pragma unroll
        for (int mt = 0; mt < 2; ++mt)
            #pragma unroll
            for (int r = 0; r < 4; ++r) {
                lsum[mt * 16 + quad * 4 + r][wv] = s[mt][r];
                lsq [mt * 16 + quad * 4 + r][wv] = ss[mt][r];
            }
    }
    __syncthreads();

    // ---- finalize LN per row, write fp32 out ----
    #pragma unroll
    for (int mt = 0; mt < 2; ++mt)
        #pragma unroll
        for (int r = 0; r < 4; ++r) {
            const int rl = mt * 16 + quad * 4 + r;
            float ts = 0.f, tss = 0.f;
            #pragma unroll
            for (int u = 0; u < 8; ++u) { ts += lsum[rl][u]; tss += lsq[rl][u]; }
            const float mean = ts * (1.0f / DM);
            const float var  = tss * (1.0f / DM) - mean * mean;
            const float rstd = rsqrtf(var + 1e-6f);
            const size_t row = (size_t)(m0 + rl);
            #pragma unroll
            for (int nt = 0; nt < 4; ++nt) {
                const int c = wv * 64 + nt * 16 + lx;
                out[row * 512 + c] =
                    (acc[mt][nt][r] - mean) * rstd * g[c] + bb[c];
            }
        }
}

// ---------------------------------------------------------------------------
extern "C" void kernel_launch(void* const* d_in, const int* in_sizes, int n_in,
                              void* d_out, int out_size, void* d_ws, size_t ws_size,
                              hipStream_t stream)
{
    (void)in_sizes; (void)n_in; (void)out_size; (void)ws_size;
    const float* hidden = (const float*)d_in[0];
    const float* rpe    = (const float*)d_in[1];
    const float* Wq     = (const float*)d_in[2];
    const float* Wk     = (const float*)d_in[3];
    const float* Wv     = (const float*)d_in[4];
    const float* fc_w   = (const float*)d_in[5];
    const float* fc_b   = (const float*)d_in[6];
    const float* ln_g   = (const float*)d_in[7];
    const float* ln_b   = (const float*)d_in[8];
    float* out = (float*)d_out;
    char* ws = (char*)d_ws;

    const size_t MB = 1024 * 1024;
    unsigned short* hb  = (unsigned short*)(ws + 0 * MB);    // 8 MB
    unsigned short* wq  = (unsigned short*)(ws + 8 * MB);
    unsigned short* wk  = (unsigned short*)(ws + 8 * MB + 512 * 1024);
    unsigned short* wv  = (unsigned short*)(ws + 9 * MB);
    unsigned short* wf  = (unsigned short*)(ws + 9 * MB + 512 * 1024);
    unsigned short* qB  = (unsigned short*)(ws + 16 * MB);   // 8 MB [B,H,N,64]
    unsigned short* kB  = (unsigned short*)(ws + 24 * MB);   // 8 MB [B,H,N,64]
    unsigned short* vtB = (unsigned short*)(ws + 32 * MB);   // 8 MB [B,H,64,N]
    unsigned short* cb  = (unsigned short*)(ws + 40 * MB);   // 8 MB ctx

    CastArgs ca;
    ca.src[0] = hidden; ca.dst[0] = hb;
    ca.src[1] = Wq;     ca.dst[1] = wq;
    ca.src[2] = Wk;     ca.dst[2] = wk;
    ca.src[3] = Wv;     ca.dst[3] = wv;
    ca.src[4] = fc_w;   ca.dst[4] = wf;
    cast_bf16_kernel<<<dim3(2048 + 4 * 128), 256, 0, stream>>>(ca);

    qkv_gemm_kernel<<<dim3(64, 12), 256, 0, stream>>>(hb, wq, wk, wv, qB, kB, vtB);
    attn_kernel<<<dim3(16, H_, B_), 256, 0, stream>>>(qB, kB, vtB, rpe, cb);
    fc_ln_kernel<<<dim3(256), 512, 0, stream>>>(cb, wf, fc_b, hidden, ln_g, ln_b, out);
}